// Round 14
// baseline (207.876 us; speedup 1.0000x reference)
//
#include <hip/hip_runtime.h>
#include <hip/hip_bf16.h>

#define N_    1024
#define L_    120
#define LQ_   30
#define D_    200
#define P_    5
#define H_    230
#define R_    96
#define BAG_  8
#define B_    128
#define EMB_  610
#define SROWS 130      // s rows: 0 = halo(-1)=0, 1..120 = pos 0..119, 121..129 = 0
#define SSTR  232      // shorts; 2-way bank spread on b128 frag reads
#define XSTR  72       // pair-buffer stride (two 32-col tiles + pad); 36dw%32=4 -> 2-way
#define NCH   21       // conv K chunks: 7 x1 + 13 {x2|x3} mixed + 1 pos

typedef __hip_bfloat16 bf16;
typedef __attribute__((ext_vector_type(8))) short short8;
typedef __attribute__((ext_vector_type(4))) short short4_;
typedef __attribute__((ext_vector_type(4))) float f32x4;

__device__ __forceinline__ float wred_sum64(float v) {
#pragma unroll
  for (int m = 32; m; m >>= 1) v += __shfl_xor(v, m, 64);
  return v;
}
__device__ __forceinline__ float wred_max64(float v) {
#pragma unroll
  for (int m = 32; m; m >>= 1) v = fmaxf(v, __shfl_xor(v, m, 64));
  return v;
}
__device__ __forceinline__ short f2b(float f) {
  bf16 h = __float2bfloat16(f);
  return __builtin_bit_cast(short, h);
}
__device__ __forceinline__ float b2f(bf16 h) { return __bfloat162float(h); }

// ---------------------------------------------------------------------------
// K0: repack conv_w f32 [H][EMB][3] -> bf16 frag-ready wt[k][cb=21][ni=16][lane][8]
//  cb 0..6   : x1 chunk, chan d = cb*32 + ccl (valid d<200)
//  cb 7..19  : mixed tile t=cb-7: ccl<16 -> x2 d=16t+ccl ; ccl>=16 -> x3 d=16t+ccl-16
//  cb 20     : pos, ccl<10 -> emb col 600+ccl
// ---------------------------------------------------------------------------
__global__ __launch_bounds__(256) void k0_prep_w(
    const float* __restrict__ conv_w, bf16* __restrict__ wt)
{
  const int idx = blockIdx.x * 256 + threadIdx.x;
  int e = idx & 7, lane = (idx >> 3) & 63;
  int fid = idx >> 9;
  int ni = fid & 15, cb = (fid >> 4) % NCH, k = fid / (NCH * 16);
  int h = ni * 16 + (lane & 15);
  int ccl = ((lane >> 4) << 3) + e;
  float v = 0.f;
  if (h < H_) {
    int emb_c = -1;
    if (cb < 7) {
      int d = cb * 32 + ccl;
      if (d < D_) emb_c = d;
    } else if (cb < 20) {
      int t = cb - 7;
      int d = 16 * t + (ccl & 15);
      if (d < D_) emb_c = (ccl < 16) ? (D_ + d) : (2 * D_ + d);
    } else if (ccl < 2 * P_) {
      emb_c = 3 * D_ + ccl;
    }
    if (emb_c >= 0) v = conv_w[(size_t)h * (EMB_ * 3) + emb_c * 3 + k];
  }
  wt[idx] = __float2bfloat16(v);
}

// ---------------------------------------------------------------------------
// KF: fused qs-attention + conv1d(k=3,SAME) + maxpool + relu -> feat [N][H]
// grid = N_, block = 1024 (16 waves, 4/SIMD, 128-VGPR budget). Wave-tile 64x32.
// Conv staged in PAIRS: wave-group wm stages tile 2p+wm; 1 barrier/period.
// R8 structure + mixed-pair B-frag prefetch issued BEFORE the barrier (the
// compiler cannot hoist loads across __syncthreads; carrying 12 frags = 48
// VGPR fits the 128-budget: 52 base + 48 ~= 100).
// ---------------------------------------------------------------------------
__global__ __launch_bounds__(1024, 4) void kf_fused(
    const int* __restrict__ X, const int* __restrict__ Q,
    const int* __restrict__ P1, const int* __restrict__ P2,
    const float* __restrict__ word_emb,
    const float* __restrict__ pos1_emb, const float* __restrict__ pos2_emb,
    const float* __restrict__ ws_w, const float* __restrict__ ws_b,
    const float* __restrict__ wq_w, const float* __restrict__ wq_b,
    const float* __restrict__ wsq_w,
    const bf16* __restrict__ wt, const float* __restrict__ conv_b,
    float* __restrict__ feat)
{
  const int n = blockIdx.x;
  const int tid = threadIdx.x;
  const int w = tid >> 6, lane = tid & 63;
  const int g = lane >> 4, c = lane & 15;
  const int wm = w >> 3;        // M-group AND stage-group (0/1)
  const int wn = w & 7;         // N-group (8): h-cols wn*32..wn*32+31
  const int w8 = w & 7;         // row-group for GEMM1/GEMM2/softmax

  __shared__ __align__(16) bf16 s_lds[SROWS][SSTR];       // 60.3 KB
  __shared__ __align__(16) bf16 qT[208][40];              // 16.6 KB  qT[d][j]
  __shared__ __align__(16) bf16 a_bf[128][40];            // 10.2 KB
  __shared__ __align__(16) bf16 xstage[2][SROWS][XSTR];   // 36.6 KB (qsw overlay)
  __shared__ __align__(16) bf16 pos_lds[L_][10];          //  2.4 KB
  __shared__ float hred[16][32];
  __shared__ float wsv[D_], wqv[D_], wsqv[D_];
  __shared__ float sdot[128], qdot[32], hmax[128], bvec[L_];
  __shared__ float q2p[4][D_];
  __shared__ int xidxs[L_], qidxs[LQ_];

  bf16 (*qsw)[SSTR] = (bf16(*)[SSTR])&xstage[0][0][0];   // [32][232], dead after GEMM1

  // ---- init: zero s_lds, qT, qsw region; load w-vectors & indices ----
  {
    const int4 z4 = {0, 0, 0, 0};
    for (int t = tid; t < SROWS * SSTR * 2 / 16; t += 1024) ((int4*)s_lds)[t] = z4;
    for (int t = tid; t < 208 * 40 * 2 / 16;     t += 1024) ((int4*)qT)[t] = z4;
    for (int t = tid; t < 32 * SSTR * 2 / 16;    t += 1024) ((int4*)qsw)[t] = z4;
  }
  if (tid < 2) qdot[30 + tid] = 0.f;
  if (tid >= 120 && tid < 128) sdot[tid] = 0.f;
  for (int t = tid; t < D_; t += 1024) { wsv[t] = ws_w[t]; wqv[t] = wq_w[t]; wsqv[t] = wsq_w[t]; }
  if (tid < L_) xidxs[tid] = X[n * L_ + tid];
  else if (tid >= 128 && tid < 128 + LQ_) qidxs[tid - 128] = Q[n * LQ_ + (tid - 128)];
  __syncthreads();

  const float wsb = ws_b[0], wqb = wq_b[0];

  // ---- phase A1: independent gathers (s, q, pos) ----
  for (int l = w; l < L_; l += 16) {
    const int idx = xidxs[l];
    if (lane < 50) {
      const int d = lane * 4;
      float4 v = *(const float4*)(word_emb + (size_t)idx * D_ + d);
      short4_ pk; pk.x = f2b(v.x); pk.y = f2b(v.y); pk.z = f2b(v.z); pk.w = f2b(v.w);
      *(short4_*)&s_lds[1 + l][d] = pk;
    }
  }
  for (int e = tid; e < L_ * 10; e += 1024) {
    int r = e / 10, p = e % 10;
    float v = (p < P_) ? pos1_emb[(size_t)P1[n * L_ + r] * P_ + p]
                       : pos2_emb[(size_t)P2[n * L_ + r] * P_ + (p - P_)];
    pos_lds[r][p] = __float2bfloat16(v);
  }
  for (int j = w; j < LQ_; j += 16) {
    const int idx = qidxs[j];
    float part = 0.f;
    if (lane < 50) {
      const int d = lane * 4;
      float4 v = *(const float4*)(word_emb + (size_t)idx * D_ + d);
      part = v.x * wqv[d] + v.y * wqv[d + 1] + v.z * wqv[d + 2] + v.w * wqv[d + 3];
      short4_ pk;
      pk.x = f2b(v.x * wsqv[d]);     pk.y = f2b(v.y * wsqv[d + 1]);
      pk.z = f2b(v.z * wsqv[d + 2]); pk.w = f2b(v.w * wsqv[d + 3]);
      *(short4_*)&qsw[j][d] = pk;
      qT[d][j]     = __float2bfloat16(v.x);
      qT[d + 1][j] = __float2bfloat16(v.y);
      qT[d + 2][j] = __float2bfloat16(v.z);
      qT[d + 3][j] = __float2bfloat16(v.w);
    }
    float sum = wred_sum64(part);
    if (lane == 0) qdot[j] = sum + wqb;
  }
  __syncthreads();

  // ---- GEMM1 (waves 0-7)  ||  sdot (waves 8-15) ----
  f32x4 acc0 = {0.f, 0.f, 0.f, 0.f}, acc1 = {0.f, 0.f, 0.f, 0.f};
  if (w < 8) {
#pragma unroll
    for (int kk = 0; kk < 7; ++kk) {
      short8 af = *(const short8*)&s_lds[1 + 16 * w + c][kk * 32 + g * 8];
      short8 b0 = *(const short8*)&qsw[c][kk * 32 + g * 8];
      short8 b1 = *(const short8*)&qsw[16 + c][kk * 32 + g * 8];
      acc0 = __builtin_amdgcn_mfma_f32_16x16x32_bf16(af, b0, acc0, 0, 0, 0);
      acc1 = __builtin_amdgcn_mfma_f32_16x16x32_bf16(af, b1, acc1, 0, 0, 0);
    }
  } else {
    const int idx = tid - 512;
    if (idx < 480) {
      const int r = idx >> 2, base = (idx & 3) * 50;
      float a = 0.f;
#pragma unroll 5
      for (int i = 0; i < 50; i += 2) {
        a += b2f(s_lds[1 + r][base + i]) * wsv[base + i];
        a += b2f(s_lds[1 + r][base + i + 1]) * wsv[base + i + 1];
      }
      a += __shfl_xor(a, 1, 64);
      a += __shfl_xor(a, 2, 64);
      if ((idx & 3) == 0) sdot[r] = a + wsb;
    }
  }
  __syncthreads();   // qsw dead after this point (waves 0-7 consumed it)

  // ---- softmax (waves 0-7)  ||  re-zero xstage (waves 8-15) ----
  if (w < 8) {
    const int rbase = 16 * w + 4 * g;
    const float qd0 = qdot[c], qd1 = qdot[16 + c];
#pragma unroll
    for (int reg = 0; reg < 4; ++reg) {
      const int r = rbase + reg;
      const float s0 = sdot[r];
      float h0 = acc0[reg] + s0 + qd0;
      float h1 = (c < 14) ? (acc1[reg] + s0 + qd1) : -1e30f;
      float m = fmaxf(h0, h1);
#pragma unroll
      for (int msk = 1; msk < 16; msk <<= 1) m = fmaxf(m, __shfl_xor(m, msk, 64));
      float e0 = expf(h0 - m);
      float e1 = (c < 14) ? expf(h1 - m) : 0.f;
      float ssum = e0 + e1;
#pragma unroll
      for (int msk = 1; msk < 16; msk <<= 1) ssum += __shfl_xor(ssum, msk, 64);
      float inv = 1.f / ssum;
      a_bf[r][c]      = __float2bfloat16(e0 * inv);
      a_bf[r][16 + c] = __float2bfloat16(e1 * inv);
      if (c == 0) hmax[r] = m;
    }
  } else {
    const int4 z4 = {0, 0, 0, 0};
    for (int t = tid - 512; t < 2 * SROWS * XSTR * 2 / 16; t += 512) ((int4*)xstage)[t] = z4;
  }
  __syncthreads();

  // ---- bvec (wave 0 only) ----
  if (w == 0) {
    float v0 = hmax[lane];
    float v1 = (lane < L_ - 64) ? hmax[64 + lane] : -1e30f;
    float m = wred_max64(fmaxf(v0, v1));
    float e0 = expf(v0 - m);
    float e1 = (lane < L_ - 64) ? expf(v1 - m) : 0.f;
    float inv = 1.f / wred_sum64(e0 + e1);
    bvec[lane] = e0 * inv;
    if (lane < L_ - 64) bvec[64 + lane] = e1 * inv;
  }
  __syncthreads();

  // ---- q2s: 4 quarters of 30 rows each ----
  {
    const int d = tid & 255, quarter = tid >> 8;
    if (d < D_) {
      const int lb = quarter * 30;
      float a0 = 0.f, a1 = 0.f;
      for (int l = 0; l < 30; l += 2) {
        a0 += bvec[lb + l]     * b2f(s_lds[1 + lb + l][d]);
        a1 += bvec[lb + l + 1] * b2f(s_lds[1 + lb + l + 1][d]);
      }
      q2p[quarter][d] = a0 + a1;
    }
  }
  __syncthreads();

  // ---- conv: 7 periods, pair-staged, 1 barrier each ----
  const short* wts = (const short*)wt;
  const short8 aft = *(const short8*)&a_bf[16 * w8 + c][g * 8];

  f32x4 acc[4][2];
#pragma unroll
  for (int i = 0; i < 4; ++i) {
    acc[i][0] = (f32x4){0.f, 0.f, 0.f, 0.f};
    acc[i][1] = (f32x4){0.f, 0.f, 0.f, 0.f};
  }

  for (int p = 0; p < 7; ++p) {
    // 1. stage pair p: group wm stages tile 2p+wm into buf slot wm
    {
      const int t = 2 * p + wm;
      bf16 (*buf)[XSTR] = xstage[p & 1];
      if (t < 13) {
        short8 bfr = *(const short8*)&qT[t * 16 + c][g * 8];
        f32x4 o = __builtin_amdgcn_mfma_f32_16x16x32_bf16(aft, bfr, (f32x4){0.f,0.f,0.f,0.f}, 0, 0, 0);
#pragma unroll
        for (int reg = 0; reg < 4; ++reg) {
          const int r = 16 * w8 + 4 * g + reg;
          if (r < L_) {
            float sv = b2f(s_lds[1 + r][t * 16 + c]);
            buf[1 + r][(t & 1) * 32 + c] = __float2bfloat16(sv * o[reg]);
          }
        }
        for (int e = tid & 511; e < L_ * 16; e += 512) {
          const int row = e >> 4, cc = e & 15, dd = t * 16 + cc;
          float v = (dd < D_)
              ? b2f(s_lds[1 + row][dd]) * (q2p[0][dd] + q2p[1][dd] + q2p[2][dd] + q2p[3][dd])
              : 0.f;
          buf[1 + row][(t & 1) * 32 + 16 + cc] = __float2bfloat16(v);
        }
      } else {   // t == 13: pos tile (wm=1, period 6) -- full-slot write
        for (int e = tid & 511; e < SROWS * 32; e += 512) {
          const int r = e >> 5, cc = e & 31;
          bf16 v = __float2bfloat16(0.f);
          if (r >= 1 && r <= L_ && cc < 2 * P_) v = pos_lds[r - 1][cc];
          buf[r][32 + cc] = v;
        }
      }
    }

    // 2. conv x1 chunk p (A from s_lds; B loaded per-k; TLP hides L2 latency)
#pragma unroll
    for (int k = 0; k < 3; ++k) {
      short8 bx0 = *(const short8*)(
          wts + (((size_t)((k * NCH + p) * 16 + wn * 2 + 0)) << 9) + lane * 8);
      short8 bx1 = *(const short8*)(
          wts + (((size_t)((k * NCH + p) * 16 + wn * 2 + 1)) << 9) + lane * 8);
#pragma unroll
      for (int mi = 0; mi < 4; ++mi) {
        short8 af = *(const short8*)&s_lds[wm * 64 + mi * 16 + c + k][p * 32 + g * 8];
        acc[mi][0] = __builtin_amdgcn_mfma_f32_16x16x32_bf16(af, bx0, acc[mi][0], 0, 0, 0);
        acc[mi][1] = __builtin_amdgcn_mfma_f32_16x16x32_bf16(af, bx1, acc[mi][1], 0, 0, 0);
      }
    }

    // 2b. prefetch the mixed-pair B-frags BEFORE the barrier (compiler cannot
    //     hoist loads across __syncthreads; they depend only on L2-hot wt).
    short8 bw[2][3][2];
#pragma unroll
    for (int s2 = 0; s2 < 2; ++s2) {
      const int t = 2 * p + s2;
      const int cb = (t < 13) ? (7 + t) : 20;
#pragma unroll
      for (int k = 0; k < 3; ++k) {
        bw[s2][k][0] = *(const short8*)(
            wts + (((size_t)((k * NCH + cb) * 16 + wn * 2 + 0)) << 9) + lane * 8);
        bw[s2][k][1] = *(const short8*)(
            wts + (((size_t)((k * NCH + cb) * 16 + wn * 2 + 1)) << 9) + lane * 8);
      }
    }
    __syncthreads();

    // 3. conv mixed pair p from staged buffer using prefetched B
    {
      bf16 (*buf)[XSTR] = xstage[p & 1];
#pragma unroll
      for (int s2 = 0; s2 < 2; ++s2) {
#pragma unroll
        for (int k = 0; k < 3; ++k) {
#pragma unroll
          for (int mi = 0; mi < 4; ++mi) {
            short8 afx = *(const short8*)&buf[wm * 64 + mi * 16 + c + k][s2 * 32 + g * 8];
            acc[mi][0] = __builtin_amdgcn_mfma_f32_16x16x32_bf16(afx, bw[s2][k][0], acc[mi][0], 0, 0, 0);
            acc[mi][1] = __builtin_amdgcn_mfma_f32_16x16x32_bf16(afx, bw[s2][k][1], acc[mi][1], 0, 0, 0);
          }
        }
      }
    }
  }

  // ---- epilogue: max over valid pos, cross-lane reduce, +bias, relu ----
  const int pbase = wm * 64 + (g << 2);
#pragma unroll
  for (int ni = 0; ni < 2; ++ni) {
    float m = -1e30f;
#pragma unroll
    for (int mi = 0; mi < 4; ++mi)
#pragma unroll
      for (int reg = 0; reg < 4; ++reg) {
        int pos = pbase + mi * 16 + reg;
        if (pos < L_) m = fmaxf(m, acc[mi][ni][reg]);
      }
    m = fmaxf(m, __shfl_xor(m, 16, 64));
    m = fmaxf(m, __shfl_xor(m, 32, 64));
    if (g == 0) hred[w][ni * 16 + c] = m;
  }
  __syncthreads();
  if (tid < H_) {
    const int wn2 = tid >> 5, x = tid & 31;
    float m = fmaxf(hred[wn2][x], hred[8 + wn2][x]);
    feat[(size_t)n * H_ + tid] = fmaxf(0.f, m + conv_b[tid]);
  }
}

// ---------------------------------------------------------------------------
// K3: bag self-attention + selective attention + final projection -> out [B][R]
// ---------------------------------------------------------------------------
__global__ __launch_bounds__(256) void k3_bag(
    const float* __restrict__ feat, const int* __restrict__ X_Rel,
    const float* __restrict__ rel_w, const float* __restrict__ rel_b,
    float* __restrict__ out)
{
  const int b = blockIdx.x;
  const int tid = threadIdx.x;
  __shared__ float f[BAG_][231];
  __shared__ float f2[BAG_][231];
  __shared__ float sc[BAG_][BAG_];
  __shared__ float relq[H_];
  __shared__ float zred[BAG_];
  __shared__ float wsel[BAG_];
  __shared__ float brep[H_];

  for (int t = tid; t < BAG_ * H_; t += 256) {
    int i = t / H_, h = t % H_;
    f[i][h] = feat[(size_t)(b * BAG_ + i) * H_ + h];
  }
  const int rel = X_Rel[b];
  for (int t = tid; t < H_; t += 256) relq[t] = rel_w[(size_t)rel * H_ + t];
  __syncthreads();

  if (tid < BAG_ * BAG_) {
    int i = tid >> 3, j = tid & 7;
    float acc = 0.f;
    for (int h = 0; h < H_; ++h) acc += f[i][h] * f[j][h];
    sc[i][j] = acc * (1.0f / sqrtf((float)H_));
  }
  __syncthreads();
  if (tid < BAG_) {
    float m = -1e30f;
    for (int j = 0; j < BAG_; ++j) m = fmaxf(m, sc[tid][j]);
    float s = 0.f;
    for (int j = 0; j < BAG_; ++j) { float e = expf(sc[tid][j] - m); sc[tid][j] = e; s += e; }
    float inv = 1.0f / s;
    for (int j = 0; j < BAG_; ++j) sc[tid][j] *= inv;
  }
  __syncthreads();
  for (int t = tid; t < BAG_ * H_; t += 256) {
    int i = t / H_, h = t % H_;
    float acc = 0.f;
#pragma unroll
    for (int j = 0; j < BAG_; ++j) acc += sc[i][j] * f[j][h];
    f2[i][h] = acc;
  }
  __syncthreads();
  if (tid < BAG_) {
    float acc = 0.f;
    for (int h = 0; h < H_; ++h) acc += f2[tid][h] * relq[h];
    zred[tid] = acc;
  }
  __syncthreads();
  if (tid == 0) {
    float m = -1e30f;
    for (int i = 0; i < BAG_; ++i) m = fmaxf(m, zred[i]);
    float s = 0.f;
    for (int i = 0; i < BAG_; ++i) { float e = expf(zred[i] - m); wsel[i] = e; s += e; }
    float inv = 1.0f / s;
    for (int i = 0; i < BAG_; ++i) wsel[i] *= inv;
  }
  __syncthreads();
  for (int t = tid; t < H_; t += 256) {
    float acc = 0.f;
#pragma unroll
    for (int i = 0; i < BAG_; ++i) acc += wsel[i] * f2[i][t];
    brep[t] = acc;
  }
  __syncthreads();
  if (tid < R_) {
    float acc = 0.f;
    for (int h = 0; h < H_; ++h) acc += brep[h] * rel_w[(size_t)tid * H_ + h];
    out[(size_t)b * R_ + tid] = acc + rel_b[tid];
  }
}

// ---------------------------------------------------------------------------
extern "C" void kernel_launch(void* const* d_in, const int* in_sizes, int n_in,
                              void* d_out, int out_size, void* d_ws, size_t ws_size,
                              hipStream_t stream)
{
  const int*   X        = (const int*)d_in[0];
  const int*   Q        = (const int*)d_in[1];
  const int*   P1       = (const int*)d_in[2];
  const int*   P2       = (const int*)d_in[3];
  // d_in[4] = X_Scope (uniform bags of 8; bag_id = i/8)
  const int*   X_Rel    = (const int*)d_in[5];
  const float* word_emb = (const float*)d_in[6];
  const float* pos1_emb = (const float*)d_in[7];
  const float* pos2_emb = (const float*)d_in[8];
  const float* ws_w     = (const float*)d_in[9];
  const float* ws_b     = (const float*)d_in[10];
  const float* wq_w     = (const float*)d_in[11];
  const float* wq_b     = (const float*)d_in[12];
  const float* wsq_w    = (const float*)d_in[13];
  // d_in[14] = wsq_b: uniform shift of h -> softmax-invariant (a and bvec), dropped
  const float* conv_w   = (const float*)d_in[15];
  const float* conv_b   = (const float*)d_in[16];
  const float* rel_w    = (const float*)d_in[17];
  const float* rel_b    = (const float*)d_in[18];

  // ws layout: feat f32 [N][H] | wt bf16 [3][21][16][64][8]
  const size_t feat_bytes = ((size_t)N_ * H_ * sizeof(float) + 255) & ~(size_t)255;
  float* feat = (float*)d_ws;
  bf16*  wt   = (bf16*)((char*)d_ws + feat_bytes);

  const int wt_elems = 3 * NCH * 16 * 64 * 8;   // 516096
  k0_prep_w<<<wt_elems / 256, 256, 0, stream>>>(conv_w, wt);
  kf_fused<<<N_, 1024, 0, stream>>>(X, Q, P1, P2, word_emb, pos1_emb, pos2_emb,
                                    ws_w, ws_b, wq_w, wq_b, wsq_w, wt, conv_b, feat);
  k3_bag<<<B_, 256, 0, stream>>>(feat, X_Rel, rel_w, rel_b, (float*)d_out);
}

// Round 15
// 204.135 us; speedup vs baseline: 1.0183x; 1.0183x over previous
//
#include <hip/hip_runtime.h>
#include <hip/hip_bf16.h>

#define N_    1024
#define L_    120
#define LQ_   30
#define D_    200
#define P_    5
#define H_    230
#define R_    96
#define BAG_  8
#define B_    128
#define EMB_  610
#define SROWS 130      // s rows: 0 = halo(-1)=0, 1..120 = pos 0..119, 121..129 = 0
#define SSTR  232      // shorts; 2-way bank spread on b128 frag reads
#define XSTR  72       // pair-buffer stride (two 32-col tiles + pad); 36dw%32=4 -> 2-way
#define NCH   21       // conv K chunks: 7 x1 + 13 {x2|x3} mixed + 1 pos

typedef __hip_bfloat16 bf16;
typedef __attribute__((ext_vector_type(8))) short short8;
typedef __attribute__((ext_vector_type(4))) short short4_;
typedef __attribute__((ext_vector_type(4))) float f32x4;

__device__ __forceinline__ float wred_sum64(float v) {
#pragma unroll
  for (int m = 32; m; m >>= 1) v += __shfl_xor(v, m, 64);
  return v;
}
__device__ __forceinline__ float wred_max64(float v) {
#pragma unroll
  for (int m = 32; m; m >>= 1) v = fmaxf(v, __shfl_xor(v, m, 64));
  return v;
}
__device__ __forceinline__ short f2b(float f) {
  bf16 h = __float2bfloat16(f);
  return __builtin_bit_cast(short, h);
}
__device__ __forceinline__ float b2f(bf16 h) { return __bfloat162float(h); }

// ---------------------------------------------------------------------------
// K0: repack conv_w f32 [H][EMB][3] -> bf16 frag-ready wt[k][cb=21][ni=16][lane][8]
//  cb 0..6   : x1 chunk, chan d = cb*32 + ccl (valid d<200)
//  cb 7..19  : mixed tile t=cb-7: ccl<16 -> x2 d=16t+ccl ; ccl>=16 -> x3 d=16t+ccl-16
//  cb 20     : pos, ccl<10 -> emb col 600+ccl
// ---------------------------------------------------------------------------
__global__ __launch_bounds__(256) void k0_prep_w(
    const float* __restrict__ conv_w, bf16* __restrict__ wt)
{
  const int idx = blockIdx.x * 256 + threadIdx.x;
  int e = idx & 7, lane = (idx >> 3) & 63;
  int fid = idx >> 9;
  int ni = fid & 15, cb = (fid >> 4) % NCH, k = fid / (NCH * 16);
  int h = ni * 16 + (lane & 15);
  int ccl = ((lane >> 4) << 3) + e;
  float v = 0.f;
  if (h < H_) {
    int emb_c = -1;
    if (cb < 7) {
      int d = cb * 32 + ccl;
      if (d < D_) emb_c = d;
    } else if (cb < 20) {
      int t = cb - 7;
      int d = 16 * t + (ccl & 15);
      if (d < D_) emb_c = (ccl < 16) ? (D_ + d) : (2 * D_ + d);
    } else if (ccl < 2 * P_) {
      emb_c = 3 * D_ + ccl;
    }
    if (emb_c >= 0) v = conv_w[(size_t)h * (EMB_ * 3) + emb_c * 3 + k];
  }
  wt[idx] = __float2bfloat16(v);
}

// ---------------------------------------------------------------------------
// KF: fused qs-attention + conv1d(k=3,SAME) + maxpool + relu -> feat [N][H]
// grid = N_, block = 1024 (16 waves, 4/SIMD, 128-VGPR budget). Wave-tile 64x32.
// Conv staged in PAIRS: wave-group wm stages tile 2p+wm; 1 barrier/period.
// Best-measured configuration (R13): R8 structure + setprio around MFMA.
// ---------------------------------------------------------------------------
__global__ __launch_bounds__(1024, 4) void kf_fused(
    const int* __restrict__ X, const int* __restrict__ Q,
    const int* __restrict__ P1, const int* __restrict__ P2,
    const float* __restrict__ word_emb,
    const float* __restrict__ pos1_emb, const float* __restrict__ pos2_emb,
    const float* __restrict__ ws_w, const float* __restrict__ ws_b,
    const float* __restrict__ wq_w, const float* __restrict__ wq_b,
    const float* __restrict__ wsq_w,
    const bf16* __restrict__ wt, const float* __restrict__ conv_b,
    float* __restrict__ feat)
{
  const int n = blockIdx.x;
  const int tid = threadIdx.x;
  const int w = tid >> 6, lane = tid & 63;
  const int g = lane >> 4, c = lane & 15;
  const int wm = w >> 3;        // M-group AND stage-group (0/1)
  const int wn = w & 7;         // N-group (8): h-cols wn*32..wn*32+31
  const int w8 = w & 7;         // row-group for GEMM1/GEMM2/softmax

  __shared__ __align__(16) bf16 s_lds[SROWS][SSTR];       // 60.3 KB
  __shared__ __align__(16) bf16 qT[208][40];              // 16.6 KB  qT[d][j]
  __shared__ __align__(16) bf16 a_bf[128][40];            // 10.2 KB
  __shared__ __align__(16) bf16 xstage[2][SROWS][XSTR];   // 36.6 KB (qsw overlay)
  __shared__ __align__(16) bf16 pos_lds[L_][10];          //  2.4 KB
  __shared__ float hred[16][32];
  __shared__ float wsv[D_], wqv[D_], wsqv[D_];
  __shared__ float sdot[128], qdot[32], hmax[128], bvec[L_];
  __shared__ float q2p[4][D_];
  __shared__ int xidxs[L_], qidxs[LQ_];

  bf16 (*qsw)[SSTR] = (bf16(*)[SSTR])&xstage[0][0][0];   // [32][232], dead after GEMM1

  // ---- init: zero s_lds, qT, qsw region; load w-vectors & indices ----
  {
    const int4 z4 = {0, 0, 0, 0};
    for (int t = tid; t < SROWS * SSTR * 2 / 16; t += 1024) ((int4*)s_lds)[t] = z4;
    for (int t = tid; t < 208 * 40 * 2 / 16;     t += 1024) ((int4*)qT)[t] = z4;
    for (int t = tid; t < 32 * SSTR * 2 / 16;    t += 1024) ((int4*)qsw)[t] = z4;
  }
  if (tid < 2) qdot[30 + tid] = 0.f;
  if (tid >= 120 && tid < 128) sdot[tid] = 0.f;
  for (int t = tid; t < D_; t += 1024) { wsv[t] = ws_w[t]; wqv[t] = wq_w[t]; wsqv[t] = wsq_w[t]; }
  if (tid < L_) xidxs[tid] = X[n * L_ + tid];
  else if (tid >= 128 && tid < 128 + LQ_) qidxs[tid - 128] = Q[n * LQ_ + (tid - 128)];
  __syncthreads();

  const float wsb = ws_b[0], wqb = wq_b[0];

  // ---- phase A1: independent gathers (s, q, pos) ----
  for (int l = w; l < L_; l += 16) {
    const int idx = xidxs[l];
    if (lane < 50) {
      const int d = lane * 4;
      float4 v = *(const float4*)(word_emb + (size_t)idx * D_ + d);
      short4_ pk; pk.x = f2b(v.x); pk.y = f2b(v.y); pk.z = f2b(v.z); pk.w = f2b(v.w);
      *(short4_*)&s_lds[1 + l][d] = pk;
    }
  }
  for (int e = tid; e < L_ * 10; e += 1024) {
    int r = e / 10, p = e % 10;
    float v = (p < P_) ? pos1_emb[(size_t)P1[n * L_ + r] * P_ + p]
                       : pos2_emb[(size_t)P2[n * L_ + r] * P_ + (p - P_)];
    pos_lds[r][p] = __float2bfloat16(v);
  }
  for (int j = w; j < LQ_; j += 16) {
    const int idx = qidxs[j];
    float part = 0.f;
    if (lane < 50) {
      const int d = lane * 4;
      float4 v = *(const float4*)(word_emb + (size_t)idx * D_ + d);
      part = v.x * wqv[d] + v.y * wqv[d + 1] + v.z * wqv[d + 2] + v.w * wqv[d + 3];
      short4_ pk;
      pk.x = f2b(v.x * wsqv[d]);     pk.y = f2b(v.y * wsqv[d + 1]);
      pk.z = f2b(v.z * wsqv[d + 2]); pk.w = f2b(v.w * wsqv[d + 3]);
      *(short4_*)&qsw[j][d] = pk;
      qT[d][j]     = __float2bfloat16(v.x);
      qT[d + 1][j] = __float2bfloat16(v.y);
      qT[d + 2][j] = __float2bfloat16(v.z);
      qT[d + 3][j] = __float2bfloat16(v.w);
    }
    float sum = wred_sum64(part);
    if (lane == 0) qdot[j] = sum + wqb;
  }
  __syncthreads();

  // ---- GEMM1 (waves 0-7)  ||  sdot (waves 8-15) ----
  f32x4 acc0 = {0.f, 0.f, 0.f, 0.f}, acc1 = {0.f, 0.f, 0.f, 0.f};
  if (w < 8) {
    __builtin_amdgcn_s_setprio(1);
#pragma unroll
    for (int kk = 0; kk < 7; ++kk) {
      short8 af = *(const short8*)&s_lds[1 + 16 * w + c][kk * 32 + g * 8];
      short8 b0 = *(const short8*)&qsw[c][kk * 32 + g * 8];
      short8 b1 = *(const short8*)&qsw[16 + c][kk * 32 + g * 8];
      acc0 = __builtin_amdgcn_mfma_f32_16x16x32_bf16(af, b0, acc0, 0, 0, 0);
      acc1 = __builtin_amdgcn_mfma_f32_16x16x32_bf16(af, b1, acc1, 0, 0, 0);
    }
    __builtin_amdgcn_s_setprio(0);
  } else {
    const int idx = tid - 512;
    if (idx < 480) {
      const int r = idx >> 2, base = (idx & 3) * 50;
      float a = 0.f;
#pragma unroll 5
      for (int i = 0; i < 50; i += 2) {
        a += b2f(s_lds[1 + r][base + i]) * wsv[base + i];
        a += b2f(s_lds[1 + r][base + i + 1]) * wsv[base + i + 1];
      }
      a += __shfl_xor(a, 1, 64);
      a += __shfl_xor(a, 2, 64);
      if ((idx & 3) == 0) sdot[r] = a + wsb;
    }
  }
  __syncthreads();   // qsw dead after this point (waves 0-7 consumed it)

  // ---- softmax (waves 0-7)  ||  re-zero xstage (waves 8-15) ----
  if (w < 8) {
    const int rbase = 16 * w + 4 * g;
    const float qd0 = qdot[c], qd1 = qdot[16 + c];
#pragma unroll
    for (int reg = 0; reg < 4; ++reg) {
      const int r = rbase + reg;
      const float s0 = sdot[r];
      float h0 = acc0[reg] + s0 + qd0;
      float h1 = (c < 14) ? (acc1[reg] + s0 + qd1) : -1e30f;
      float m = fmaxf(h0, h1);
#pragma unroll
      for (int msk = 1; msk < 16; msk <<= 1) m = fmaxf(m, __shfl_xor(m, msk, 64));
      float e0 = expf(h0 - m);
      float e1 = (c < 14) ? expf(h1 - m) : 0.f;
      float ssum = e0 + e1;
#pragma unroll
      for (int msk = 1; msk < 16; msk <<= 1) ssum += __shfl_xor(ssum, msk, 64);
      float inv = 1.f / ssum;
      a_bf[r][c]      = __float2bfloat16(e0 * inv);
      a_bf[r][16 + c] = __float2bfloat16(e1 * inv);
      if (c == 0) hmax[r] = m;
    }
  } else {
    const int4 z4 = {0, 0, 0, 0};
    for (int t = tid - 512; t < 2 * SROWS * XSTR * 2 / 16; t += 512) ((int4*)xstage)[t] = z4;
  }
  __syncthreads();

  // ---- bvec (wave 0 only) ----
  if (w == 0) {
    float v0 = hmax[lane];
    float v1 = (lane < L_ - 64) ? hmax[64 + lane] : -1e30f;
    float m = wred_max64(fmaxf(v0, v1));
    float e0 = expf(v0 - m);
    float e1 = (lane < L_ - 64) ? expf(v1 - m) : 0.f;
    float inv = 1.f / wred_sum64(e0 + e1);
    bvec[lane] = e0 * inv;
    if (lane < L_ - 64) bvec[64 + lane] = e1 * inv;
  }
  __syncthreads();

  // ---- q2s: 4 quarters of 30 rows each ----
  {
    const int d = tid & 255, quarter = tid >> 8;
    if (d < D_) {
      const int lb = quarter * 30;
      float a0 = 0.f, a1 = 0.f;
      for (int l = 0; l < 30; l += 2) {
        a0 += bvec[lb + l]     * b2f(s_lds[1 + lb + l][d]);
        a1 += bvec[lb + l + 1] * b2f(s_lds[1 + lb + l + 1][d]);
      }
      q2p[quarter][d] = a0 + a1;
    }
  }
  __syncthreads();

  // ---- conv: 7 periods, pair-staged, 1 barrier each ----
  const short* wts = (const short*)wt;
  const short8 aft = *(const short8*)&a_bf[16 * w8 + c][g * 8];

  f32x4 acc[4][2];
#pragma unroll
  for (int i = 0; i < 4; ++i) {
    acc[i][0] = (f32x4){0.f, 0.f, 0.f, 0.f};
    acc[i][1] = (f32x4){0.f, 0.f, 0.f, 0.f};
  }

  for (int p = 0; p < 7; ++p) {
    // 1. stage pair p: group wm stages tile 2p+wm into buf slot wm
    {
      const int t = 2 * p + wm;
      bf16 (*buf)[XSTR] = xstage[p & 1];
      if (t < 13) {
        short8 bfr = *(const short8*)&qT[t * 16 + c][g * 8];
        f32x4 o = __builtin_amdgcn_mfma_f32_16x16x32_bf16(aft, bfr, (f32x4){0.f,0.f,0.f,0.f}, 0, 0, 0);
#pragma unroll
        for (int reg = 0; reg < 4; ++reg) {
          const int r = 16 * w8 + 4 * g + reg;
          if (r < L_) {
            float sv = b2f(s_lds[1 + r][t * 16 + c]);
            buf[1 + r][(t & 1) * 32 + c] = __float2bfloat16(sv * o[reg]);
          }
        }
        for (int e = tid & 511; e < L_ * 16; e += 512) {
          const int row = e >> 4, cc = e & 15, dd = t * 16 + cc;
          float v = (dd < D_)
              ? b2f(s_lds[1 + row][dd]) * (q2p[0][dd] + q2p[1][dd] + q2p[2][dd] + q2p[3][dd])
              : 0.f;
          buf[1 + row][(t & 1) * 32 + 16 + cc] = __float2bfloat16(v);
        }
      } else {   // t == 13: pos tile (wm=1, period 6) -- full-slot write
        for (int e = tid & 511; e < SROWS * 32; e += 512) {
          const int r = e >> 5, cc = e & 31;
          bf16 v = __float2bfloat16(0.f);
          if (r >= 1 && r <= L_ && cc < 2 * P_) v = pos_lds[r - 1][cc];
          buf[r][32 + cc] = v;
        }
      }
    }

    // 2. conv x1 chunk p (A from s_lds; B loaded per-k; TLP hides L2 latency)
    __builtin_amdgcn_s_setprio(1);
#pragma unroll
    for (int k = 0; k < 3; ++k) {
      short8 bx0 = *(const short8*)(
          wts + (((size_t)((k * NCH + p) * 16 + wn * 2 + 0)) << 9) + lane * 8);
      short8 bx1 = *(const short8*)(
          wts + (((size_t)((k * NCH + p) * 16 + wn * 2 + 1)) << 9) + lane * 8);
#pragma unroll
      for (int mi = 0; mi < 4; ++mi) {
        short8 af = *(const short8*)&s_lds[wm * 64 + mi * 16 + c + k][p * 32 + g * 8];
        acc[mi][0] = __builtin_amdgcn_mfma_f32_16x16x32_bf16(af, bx0, acc[mi][0], 0, 0, 0);
        acc[mi][1] = __builtin_amdgcn_mfma_f32_16x16x32_bf16(af, bx1, acc[mi][1], 0, 0, 0);
      }
    }
    __builtin_amdgcn_s_setprio(0);
    __syncthreads();

    // 3. conv mixed pair p from staged buffer (B loaded inline per k,s2)
    {
      bf16 (*buf)[XSTR] = xstage[p & 1];
      __builtin_amdgcn_s_setprio(1);
#pragma unroll
      for (int s2 = 0; s2 < 2; ++s2) {
        const int t = 2 * p + s2;
        const int cb = (t < 13) ? (7 + t) : 20;
#pragma unroll
        for (int k = 0; k < 3; ++k) {
          short8 bw0 = *(const short8*)(
              wts + (((size_t)((k * NCH + cb) * 16 + wn * 2 + 0)) << 9) + lane * 8);
          short8 bw1 = *(const short8*)(
              wts + (((size_t)((k * NCH + cb) * 16 + wn * 2 + 1)) << 9) + lane * 8);
#pragma unroll
          for (int mi = 0; mi < 4; ++mi) {
            short8 afx = *(const short8*)&buf[wm * 64 + mi * 16 + c + k][s2 * 32 + g * 8];
            acc[mi][0] = __builtin_amdgcn_mfma_f32_16x16x32_bf16(afx, bw0, acc[mi][0], 0, 0, 0);
            acc[mi][1] = __builtin_amdgcn_mfma_f32_16x16x32_bf16(afx, bw1, acc[mi][1], 0, 0, 0);
          }
        }
      }
      __builtin_amdgcn_s_setprio(0);
    }
  }

  // ---- epilogue: max over valid pos, cross-lane reduce, +bias, relu ----
  const int pbase = wm * 64 + (g << 2);
#pragma unroll
  for (int ni = 0; ni < 2; ++ni) {
    float m = -1e30f;
#pragma unroll
    for (int mi = 0; mi < 4; ++mi)
#pragma unroll
      for (int reg = 0; reg < 4; ++reg) {
        int pos = pbase + mi * 16 + reg;
        if (pos < L_) m = fmaxf(m, acc[mi][ni][reg]);
      }
    m = fmaxf(m, __shfl_xor(m, 16, 64));
    m = fmaxf(m, __shfl_xor(m, 32, 64));
    if (g == 0) hred[w][ni * 16 + c] = m;
  }
  __syncthreads();
  if (tid < H_) {
    const int wn2 = tid >> 5, x = tid & 31;
    float m = fmaxf(hred[wn2][x], hred[8 + wn2][x]);
    feat[(size_t)n * H_ + tid] = fmaxf(0.f, m + conv_b[tid]);
  }
}

// ---------------------------------------------------------------------------
// K3: bag self-attention + selective attention + final projection -> out [B][R]
// ---------------------------------------------------------------------------
__global__ __launch_bounds__(256) void k3_bag(
    const float* __restrict__ feat, const int* __restrict__ X_Rel,
    const float* __restrict__ rel_w, const float* __restrict__ rel_b,
    float* __restrict__ out)
{
  const int b = blockIdx.x;
  const int tid = threadIdx.x;
  __shared__ float f[BAG_][231];
  __shared__ float f2[BAG_][231];
  __shared__ float sc[BAG_][BAG_];
  __shared__ float relq[H_];
  __shared__ float zred[BAG_];
  __shared__ float wsel[BAG_];
  __shared__ float brep[H_];

  for (int t = tid; t < BAG_ * H_; t += 256) {
    int i = t / H_, h = t % H_;
    f[i][h] = feat[(size_t)(b * BAG_ + i) * H_ + h];
  }
  const int rel = X_Rel[b];
  for (int t = tid; t < H_; t += 256) relq[t] = rel_w[(size_t)rel * H_ + t];
  __syncthreads();

  if (tid < BAG_ * BAG_) {
    int i = tid >> 3, j = tid & 7;
    float acc = 0.f;
    for (int h = 0; h < H_; ++h) acc += f[i][h] * f[j][h];
    sc[i][j] = acc * (1.0f / sqrtf((float)H_));
  }
  __syncthreads();
  if (tid < BAG_) {
    float m = -1e30f;
    for (int j = 0; j < BAG_; ++j) m = fmaxf(m, sc[tid][j]);
    float s = 0.f;
    for (int j = 0; j < BAG_; ++j) { float e = expf(sc[tid][j] - m); sc[tid][j] = e; s += e; }
    float inv = 1.0f / s;
    for (int j = 0; j < BAG_; ++j) sc[tid][j] *= inv;
  }
  __syncthreads();
  for (int t = tid; t < BAG_ * H_; t += 256) {
    int i = t / H_, h = t % H_;
    float acc = 0.f;
#pragma unroll
    for (int j = 0; j < BAG_; ++j) acc += sc[i][j] * f[j][h];
    f2[i][h] = acc;
  }
  __syncthreads();
  if (tid < BAG_) {
    float acc = 0.f;
    for (int h = 0; h < H_; ++h) acc += f2[tid][h] * relq[h];
    zred[tid] = acc;
  }
  __syncthreads();
  if (tid == 0) {
    float m = -1e30f;
    for (int i = 0; i < BAG_; ++i) m = fmaxf(m, zred[i]);
    float s = 0.f;
    for (int i = 0; i < BAG_; ++i) { float e = expf(zred[i] - m); wsel[i] = e; s += e; }
    float inv = 1.0f / s;
    for (int i = 0; i < BAG_; ++i) wsel[i] *= inv;
  }
  __syncthreads();
  for (int t = tid; t < H_; t += 256) {
    float acc = 0.f;
#pragma unroll
    for (int i = 0; i < BAG_; ++i) acc += wsel[i] * f2[i][t];
    brep[t] = acc;
  }
  __syncthreads();
  if (tid < R_) {
    float acc = 0.f;
    for (int h = 0; h < H_; ++h) acc += brep[h] * rel_w[(size_t)tid * H_ + h];
    out[(size_t)b * R_ + tid] = acc + rel_b[tid];
  }
}

// ---------------------------------------------------------------------------
extern "C" void kernel_launch(void* const* d_in, const int* in_sizes, int n_in,
                              void* d_out, int out_size, void* d_ws, size_t ws_size,
                              hipStream_t stream)
{
  const int*   X        = (const int*)d_in[0];
  const int*   Q        = (const int*)d_in[1];
  const int*   P1       = (const int*)d_in[2];
  const int*   P2       = (const int*)d_in[3];
  // d_in[4] = X_Scope (uniform bags of 8; bag_id = i/8)
  const int*   X_Rel    = (const int*)d_in[5];
  const float* word_emb = (const float*)d_in[6];
  const float* pos1_emb = (const float*)d_in[7];
  const float* pos2_emb = (const float*)d_in[8];
  const float* ws_w     = (const float*)d_in[9];
  const float* ws_b     = (const float*)d_in[10];
  const float* wq_w     = (const float*)d_in[11];
  const float* wq_b     = (const float*)d_in[12];
  const float* wsq_w    = (const float*)d_in[13];
  // d_in[14] = wsq_b: uniform shift of h -> softmax-invariant (a and bvec), dropped
  const float* conv_w   = (const float*)d_in[15];
  const float* conv_b   = (const float*)d_in[16];
  const float* rel_w    = (const float*)d_in[17];
  const float* rel_b    = (const float*)d_in[18];

  // ws layout: feat f32 [N][H] | wt bf16 [3][21][16][64][8]
  const size_t feat_bytes = ((size_t)N_ * H_ * sizeof(float) + 255) & ~(size_t)255;
  float* feat = (float*)d_ws;
  bf16*  wt   = (bf16*)((char*)d_ws + feat_bytes);

  const int wt_elems = 3 * NCH * 16 * 64 * 8;   // 516096
  k0_prep_w<<<wt_elems / 256, 256, 0, stream>>>(conv_w, wt);
  kf_fused<<<N_, 1024, 0, stream>>>(X, Q, P1, P2, word_emb, pos1_emb, pos2_emb,
                                    ws_w, ws_b, wq_w, wq_b, wsq_w, wt, conv_b, feat);
  k3_bag<<<B_, 256, 0, stream>>>(feat, X_Rel, rel_w, rel_b, (float*)d_out);
}